// Round 7
// baseline (138.232 us; speedup 1.0000x reference)
//
#include <hip/hip_runtime.h>

// MaxMinComp: out[b,o] = max_i min(x[b,i], W[i,o]); B=1024, IN=OUT=512, fp32.
// fp16 packed tropical GEMM, VOP3P op_sel broadcast: 3 ds_read_b128 / 64 pk.
//
// R6 measured (8-rep): 11.7us/rep, VALUBusy 64% => VALU-busy ~7.5us/rep —
// 2x the 2-cyc model, invariant across R4/R6 structures. Theory: packed
// *integer* u16 min/max is half-rate (4 cyc); packed FP16 is the fast path.
// R7 = v6 with v_pk_min_f16/v_pk_max_f16 (numerically identical: values in
// [0,1), no NaN, +0.0 acc init). Single variable; REPS=8 kept for counters.

typedef unsigned int u32;
typedef u32 u32x2 __attribute__((ext_vector_type(2)));
typedef u32 u32x4 __attribute__((ext_vector_type(4)));
typedef float f4 __attribute__((ext_vector_type(4)));
typedef float f2 __attribute__((ext_vector_type(2)));
typedef __fp16 h2 __attribute__((ext_vector_type(2)));

#define XB 8192               // x pairs: 64 kp * 32 rows * 4B
#define WB 16384              // w: 128 k * 32 colpairs * 4B
#define BUFB (XB + WB)        // 24576 per buffer, double-buffered
#define REPS 8

static __device__ __forceinline__ u32 pkcvt(float a, float b) {
  return __builtin_bit_cast(u32, __builtin_amdgcn_cvt_pkrtz(a, b));
}
static __device__ __forceinline__ u32 pkmax(u32 a, u32 b) {
  u32 d; asm("v_pk_max_f16 %0, %1, %2" : "=v"(d) : "v"(a), "v"(b)); return d;
}
static __device__ __forceinline__ u32 pkmin_bl(u32 x, u32 w) {  // min(bcast(x.lo), w)
  u32 d;
  asm("v_pk_min_f16 %0, %1, %2 op_sel:[0,0] op_sel_hi:[0,1]"
      : "=v"(d) : "v"(x), "v"(w));
  return d;
}
static __device__ __forceinline__ u32 pkmin_bh(u32 x, u32 w) {  // min(bcast(x.hi), w)
  u32 d;
  asm("v_pk_min_f16 %0, %1, %2 op_sel:[1,0] op_sel_hi:[1,1]"
      : "=v"(d) : "v"(x), "v"(w));
  return d;
}

__global__ __launch_bounds__(1024, 4) void maxmin_v7(const float* __restrict__ X,
                                                     const float* __restrict__ W,
                                                     float* __restrict__ Out) {
  __shared__ __align__(16) char smem[65536];  // 48KB staging dbuf; 64KB overlay

  const int tid  = threadIdx.x;
  const int wv   = tid >> 6;   // wave = k-slice 0..15
  const int lane = tid & 63;
  const int ty   = lane >> 3;  // rows 4*ty .. 4*ty+3
  const int tx   = lane & 7;   // colpairs 4*tx .. 4*tx+3
  const int b0   = blockIdx.x * 32;
  const int o0   = blockIdx.y * 64;

  // x staging: r = tid&31 (per-phase banks = r: conflict-free LDS writes),
  // kq = tid>>5 (0..31) indexes float4 groups within the 128-k chunk.
  const int xr  = tid & 31;
  const int xkq = tid >> 5;
  const float* xg = X + (b0 + xr) * 512 + xkq * 4;
  const int xw0 = (2 * xkq) * 128 + 4 * xr;  // pair kp=2kq; +128 for kp+1

  // w staging: rows kk=tid>>4 (0..63) and kk+64; coalesced; 2-way/phase = free.
  const int wkk = tid >> 4;
  const int wc4 = tid & 15;
  const float* wg = W + wkk * 512 + o0 + wc4 * 4;
  const int ww0 = XB + wkk * 128 + wc4 * 8;

  // compute-side read offsets (broadcast reads need no swizzle)
  const int xro = 16 * ty;
  const int wro = XB + 16 * tx;

  auto stage = [&](char* buf, f4 xv, f4 wa, f4 wb) {
    *(u32*)(buf + xw0)       = pkcvt(xv.x, xv.y);
    *(u32*)(buf + xw0 + 128) = pkcvt(xv.z, xv.w);
    u32x2 wpa = {pkcvt(wa.x, wa.y), pkcvt(wa.z, wa.w)};
    *(u32x2*)(buf + ww0) = wpa;
    u32x2 wpb = {pkcvt(wb.x, wb.y), pkcvt(wb.z, wb.w)};
    *(u32x2*)(buf + ww0 + 64 * 128) = wpb;
  };

#pragma unroll 1
  for (int rep = 0; rep < REPS; ++rep) {
    asm volatile("" ::: "memory");  // block cross-rep CSE

    u32 acc[4][4] = {};

    {
      f4 xv = *(const f4*)xg;
      f4 wa = *(const f4*)wg;
      f4 wb = *(const f4*)(wg + 64 * 512);
      stage(smem, xv, wa, wb);
    }
    __syncthreads();

    for (int c = 0; c < 4; ++c) {
      f4 nx = {}, na = {}, nb = {};
      if (c < 3) {
        nx = *(const f4*)(xg + (c + 1) * 128);
        na = *(const f4*)(wg + (c + 1) * 128 * 512);
        nb = *(const f4*)(wg + (c + 1) * 128 * 512 + 64 * 512);
      }
      const char* buf = smem + (c & 1) * BUFB;
#pragma unroll
      for (int q = 0; q < 4; ++q) {
        const int kp = 4 * wv + q;
        u32x4 xv = *(const u32x4*)(buf + kp * 128 + xro);
        u32x4 wl = *(const u32x4*)(buf + wro + (2 * kp) * 128);
        u32x4 wh = *(const u32x4*)(buf + wro + (2 * kp + 1) * 128);
#pragma unroll
        for (int j = 0; j < 4; ++j)
#pragma unroll
          for (int cc = 0; cc < 4; ++cc) {
            acc[j][cc] = pkmax(acc[j][cc], pkmin_bl(xv[j], wl[cc]));
            acc[j][cc] = pkmax(acc[j][cc], pkmin_bh(xv[j], wh[cc]));
          }
      }
      if (c < 3) stage(smem + ((c + 1) & 1) * BUFB, nx, na, nb);
      __syncthreads();
    }

    // epilogue: 16 wave-partials -> overlay [wv][row][colpair]
#pragma unroll
    for (int j = 0; j < 4; ++j) {
      u32x4 v = {acc[j][0], acc[j][1], acc[j][2], acc[j][3]};
      *(u32x4*)(smem + wv * 4096 + (4 * ty + j) * 128 + tx * 16) = v;
    }
    __syncthreads();

    const int row = tid >> 5;
    const int cp  = tid & 31;
    const int cb  = row * 128 + cp * 4;
    u32 m = *(const u32*)(smem + cb);
#pragma unroll
    for (int g = 1; g < 16; ++g) m = pkmax(m, *(const u32*)(smem + g * 4096 + cb));
    h2 hm = __builtin_bit_cast(h2, m);
    f2 o = {(float)hm.x, (float)hm.y};
    *(f2*)(Out + (b0 + row) * 512 + o0 + cp * 2) = o;

    __syncthreads();  // protect overlay before next rep restages
  }
}

extern "C" void kernel_launch(void* const* d_in, const int* in_sizes, int n_in,
                              void* d_out, int out_size, void* d_ws, size_t ws_size,
                              hipStream_t stream) {
  const float* x = (const float*)d_in[0];
  const float* w = (const float*)d_in[1];
  float* out = (float*)d_out;
  (void)in_sizes; (void)n_in; (void)out_size; (void)d_ws; (void)ws_size;
  dim3 grid(1024 / 32, 512 / 64);  // 256 blocks = 1/CU, 16 waves each
  maxmin_v7<<<grid, 1024, 0, stream>>>(x, w, out);
}

// Round 8
// 67.895 us; speedup vs baseline: 2.0360x; 2.0360x over previous
//
#include <hip/hip_runtime.h>

// MaxMinComp: out[b,o] = max_i min(x[b,i], W[i,o]); B=1024, IN=OUT=512, fp32.
// fp16 packed tropical GEMM, VOP3P op_sel broadcast: 3 ds_read_b128 / 64 pk.
//
// Measured history: R4 14.25us/rep -> R6/R7 11.3us/rep steady (restructure +
// conflict fix); u16 vs f16 pk identical (R7); VALU-busy ~7.5us/rep invariant
// => ~2x the 2.4GHz model: low clock during short dispatches (unfixable).
// Single-shot bench = ~41us fixed harness + ~25us dispatch-visible, of which
// steady compute is only ~11us; rest = launch/clock + COLD-L2 serialization
// (poison fill flushes L2; chunk loads were issued barrier-by-barrier).
// R8: REPS=1 ship + prefetch-ALL (12x16B global loads in prologue, stage each
// chunk from registers) -> one cold round-trip instead of four.

typedef unsigned int u32;
typedef u32 u32x2 __attribute__((ext_vector_type(2)));
typedef u32 u32x4 __attribute__((ext_vector_type(4)));
typedef float f4 __attribute__((ext_vector_type(4)));
typedef float f2 __attribute__((ext_vector_type(2)));
typedef __fp16 h2 __attribute__((ext_vector_type(2)));

#define XB 8192               // x pairs: 64 kp * 32 rows * 4B
#define WB 16384              // w: 128 k * 32 colpairs * 4B
#define BUFB (XB + WB)        // 24576 per buffer, double-buffered

static __device__ __forceinline__ u32 pkcvt(float a, float b) {
  return __builtin_bit_cast(u32, __builtin_amdgcn_cvt_pkrtz(a, b));
}
static __device__ __forceinline__ u32 pkmax(u32 a, u32 b) {
  u32 d; asm("v_pk_max_f16 %0, %1, %2" : "=v"(d) : "v"(a), "v"(b)); return d;
}
static __device__ __forceinline__ u32 pkmin_bl(u32 x, u32 w) {  // min(bcast(x.lo), w)
  u32 d;
  asm("v_pk_min_f16 %0, %1, %2 op_sel:[0,0] op_sel_hi:[0,1]"
      : "=v"(d) : "v"(x), "v"(w));
  return d;
}
static __device__ __forceinline__ u32 pkmin_bh(u32 x, u32 w) {  // min(bcast(x.hi), w)
  u32 d;
  asm("v_pk_min_f16 %0, %1, %2 op_sel:[1,0] op_sel_hi:[1,1]"
      : "=v"(d) : "v"(x), "v"(w));
  return d;
}

__global__ __launch_bounds__(1024, 4) void maxmin_v8(const float* __restrict__ X,
                                                     const float* __restrict__ W,
                                                     float* __restrict__ Out) {
  __shared__ __align__(16) char smem[65536];  // 48KB staging dbuf; 64KB overlay

  const int tid  = threadIdx.x;
  const int wv   = tid >> 6;   // wave = k-slice 0..15
  const int lane = tid & 63;
  const int ty   = lane >> 3;  // rows 4*ty .. 4*ty+3
  const int tx   = lane & 7;   // colpairs 4*tx .. 4*tx+3
  const int b0   = blockIdx.x * 32;
  const int o0   = blockIdx.y * 64;

  // x staging: r = tid&31 (per-phase LDS write banks = r: conflict-free),
  // kq = tid>>5 (0..31) indexes float4 groups within the 128-k chunk.
  const int xr  = tid & 31;
  const int xkq = tid >> 5;
  const float* xg = X + (b0 + xr) * 512 + xkq * 4;
  const int xw0 = (2 * xkq) * 128 + 4 * xr;  // pair kp=2kq; +128 for kp+1

  // w staging: rows kk=tid>>4 (0..63) and kk+64; coalesced; 2-way/phase free.
  const int wkk = tid >> 4;
  const int wc4 = tid & 15;
  const float* wg = W + wkk * 512 + o0 + wc4 * 4;
  const int ww0 = XB + wkk * 128 + wc4 * 8;

  // prefetch-ALL: 12 outstanding 16B loads; one cold round-trip total.
  f4 xv[4], wa[4], wb[4];
#pragma unroll
  for (int c = 0; c < 4; ++c) {
    xv[c] = *(const f4*)(xg + c * 128);
    wa[c] = *(const f4*)(wg + c * 128 * 512);
    wb[c] = *(const f4*)(wg + c * 128 * 512 + 64 * 512);
  }

  // compute-side read offsets (broadcast reads need no swizzle)
  const int xro = 16 * ty;
  const int wro = XB + 16 * tx;

  auto stage = [&](char* buf, f4 xvv, f4 waa, f4 wbb) {
    *(u32*)(buf + xw0)       = pkcvt(xvv.x, xvv.y);
    *(u32*)(buf + xw0 + 128) = pkcvt(xvv.z, xvv.w);
    u32x2 wpa = {pkcvt(waa.x, waa.y), pkcvt(waa.z, waa.w)};
    *(u32x2*)(buf + ww0) = wpa;
    u32x2 wpb = {pkcvt(wbb.x, wbb.y), pkcvt(wbb.z, wbb.w)};
    *(u32x2*)(buf + ww0 + 64 * 128) = wpb;
  };

  u32 acc[4][4] = {};

  stage(smem, xv[0], wa[0], wb[0]);
  __syncthreads();

  for (int c = 0; c < 4; ++c) {
    const char* buf = smem + (c & 1) * BUFB;
#pragma unroll
    for (int q = 0; q < 4; ++q) {
      const int kp = 4 * wv + q;
      u32x4 xq = *(const u32x4*)(buf + kp * 128 + xro);
      u32x4 wl = *(const u32x4*)(buf + wro + (2 * kp) * 128);
      u32x4 wh = *(const u32x4*)(buf + wro + (2 * kp + 1) * 128);
#pragma unroll
      for (int j = 0; j < 4; ++j)
#pragma unroll
        for (int cc = 0; cc < 4; ++cc) {
          acc[j][cc] = pkmax(acc[j][cc], pkmin_bl(xq[j], wl[cc]));
          acc[j][cc] = pkmax(acc[j][cc], pkmin_bh(xq[j], wh[cc]));
        }
    }
    if (c < 3) stage(smem + ((c + 1) & 1) * BUFB, xv[c + 1], wa[c + 1], wb[c + 1]);
    __syncthreads();
  }

  // epilogue: 16 wave-partials -> overlay [wv][row][colpair]
#pragma unroll
  for (int j = 0; j < 4; ++j) {
    u32x4 v = {acc[j][0], acc[j][1], acc[j][2], acc[j][3]};
    *(u32x4*)(smem + wv * 4096 + (4 * ty + j) * 128 + tx * 16) = v;
  }
  __syncthreads();

  const int row = tid >> 5;
  const int cp  = tid & 31;
  const int cb  = row * 128 + cp * 4;
  u32 m = *(const u32*)(smem + cb);
#pragma unroll
  for (int g = 1; g < 16; ++g) m = pkmax(m, *(const u32*)(smem + g * 4096 + cb));
  h2 hm = __builtin_bit_cast(h2, m);
  f2 o = {(float)hm.x, (float)hm.y};
  *(f2*)(Out + (b0 + row) * 512 + o0 + cp * 2) = o;
}

extern "C" void kernel_launch(void* const* d_in, const int* in_sizes, int n_in,
                              void* d_out, int out_size, void* d_ws, size_t ws_size,
                              hipStream_t stream) {
  const float* x = (const float*)d_in[0];
  const float* w = (const float*)d_in[1];
  float* out = (float*)d_out;
  (void)in_sizes; (void)n_in; (void)out_size; (void)d_ws; (void)ws_size;
  dim3 grid(1024 / 32, 512 / 64);  // 256 blocks = 1/CU, 16 waves each
  maxmin_v8<<<grid, 1024, 0, stream>>>(x, w, out);
}